// Round 5
// baseline (468.243 us; speedup 1.0000x reference)
//
#include <hip/hip_runtime.h>

// Integration_block: scaling-and-squaring SVF integration.
// flow = SVF * 2^-7; 7x: flow = flow + trilerp(flow, p + flow), zeros padding.
// Shape (1, 3, 160, 192, 224) fp32, planar channels in input/output.
//
// Strategy: each 32x8x2 block stages its 36x12x6 halo-2 neighborhood into LDS
// with coalesced, address-independent loads (zero-filled out-of-volume, which
// IS the zeros padding), then trilerps from LDS. One global memory round per
// pass instead of own-load -> dependent scattered gathers. Samples that leave
// the staged box (possible only in late iterations' tails) fall back to a
// per-corner global gather. Iter 0 stages planar SVF with the 1/128 scale
// folded in (trilerp is linear), eliminating the separate scale pass.

#define D_ 160
#define H_ 192
#define W_ 224
static constexpr int NV = D_ * H_ * W_;
static constexpr float S_ = 0.0078125f;   // 2^-7
static constexpr int ROWS = 3 * W_;       // interleaved row stride (floats)

#define TW 32
#define TH 8
#define TD 2
#define HALO 2
static constexpr int SW = TW + 2 * HALO;   // 36
static constexpr int SH = TH + 2 * HALO;   // 12
static constexpr int SD = TD + 2 * HALO;   // 6
static constexpr int SWF = 3 * SW;         // 108 floats per staged (d,h) row
static constexpr int NREG = SD * SH * SWF; // 7776 floats = 31104 B
static constexpr int NVOX = SD * SH * SW;  // 2592 voxels

template <int FIRST, int PLANAR_OUT>
__global__ __launch_bounds__(512) void compose_k(const float* __restrict__ in,
                                                 float* __restrict__ out) {
    __shared__ float lds[NREG];
    const int tid = threadIdx.z * (TW * TH) + threadIdx.y * TW + threadIdx.x;
    const int W0 = blockIdx.x * TW, H0 = blockIdx.y * TH, D0 = blockIdx.z * TD;
    const int Dlo = D0 - HALO, Hlo = H0 - HALO, Wlo = W0 - HALO;

    if (FIRST) {
        // planar SVF -> interleaved LDS, scale folded in
        float v0[6], v1[6], v2[6];
#pragma unroll
        for (int i = 0; i < 6; ++i) {
            const int u = tid + i * 512;
            v0[i] = v1[i] = v2[i] = 0.f;
            if (u < NVOX) {
                const int row = u / SW, wc = u - row * SW;
                const int dd = row / SH, hh = row - dd * SH;
                const int gd = Dlo + dd, gh = Hlo + hh, gw = Wlo + wc;
                if ((unsigned)gd < (unsigned)D_ && (unsigned)gh < (unsigned)H_ &&
                    (unsigned)gw < (unsigned)W_) {
                    const int b = (gd * H_ + gh) * W_ + gw;
                    v0[i] = in[b] * S_;
                    v1[i] = in[NV + b] * S_;
                    v2[i] = in[2 * NV + b] * S_;
                }
            }
        }
#pragma unroll
        for (int i = 0; i < 6; ++i) {
            const int u = tid + i * 512;
            if (u < NVOX) {
                lds[3 * u] = v0[i];
                lds[3 * u + 1] = v1[i];
                lds[3 * u + 2] = v2[i];
            }
        }
    } else {
        // interleaved flow -> LDS (straight float copy of the halo region)
        float vals[16];
#pragma unroll
        for (int i = 0; i < 16; ++i) {
            const int u = tid + i * 512;
            vals[i] = 0.f;
            if (u < NREG) {
                const int row = u / SWF, col = u - row * SWF;
                const int dd = row / SH, hh = row - dd * SH;
                const int gd = Dlo + dd, gh = Hlo + hh;
                const int wf = 3 * Wlo + col;   // float index within global row
                if ((unsigned)gd < (unsigned)D_ && (unsigned)gh < (unsigned)H_ &&
                    (unsigned)wf < (unsigned)(3 * W_)) {
                    vals[i] = in[(gd * H_ + gh) * ROWS + wf];
                }
            }
        }
#pragma unroll
        for (int i = 0; i < 16; ++i) {
            const int u = tid + i * 512;
            if (u < NREG) lds[u] = vals[i];
        }
    }
    __syncthreads();

    const int tw = threadIdx.x, th = threadIdx.y, tdz = threadIdx.z;
    const int w = W0 + tw, h = H0 + th, d = D0 + tdz;
    const int idx = (d * H_ + h) * W_ + w;

    const int lown = ((tdz + HALO) * SH + (th + HALO)) * SWF + (tw + HALO) * 3;
    const float f0 = lds[lown], f1 = lds[lown + 1], f2 = lds[lown + 2];

    const float pd = (float)d + f0;
    const float ph = (float)h + f1;
    const float pw = (float)w + f2;
    const float d0f = floorf(pd), h0f = floorf(ph), w0f = floorf(pw);
    const int d0 = (int)d0f, h0 = (int)h0f, w0 = (int)w0f;
    const float fd = pd - d0f, fh = ph - h0f, fw = pw - w0f;

    const int ld = d0 - Dlo, lh = h0 - Hlo, lw = w0 - Wlo;

    float acc0, acc1, acc2;

    if ((unsigned)ld <= (unsigned)(SD - 2) && (unsigned)lh <= (unsigned)(SH - 2) &&
        (unsigned)lw <= (unsigned)(SW - 2)) {
        // all 8 corners staged (incl. zero padding) -> pure LDS trilerp
        const int b = (ld * SH + lh) * SWF + 3 * lw;
        const float* r00 = lds + b;
        const float* r01 = lds + b + SWF;
        const float* r10 = lds + b + SH * SWF;
        const float* r11 = lds + b + SH * SWF + SWF;

        const float ww1 = fw, ww0 = 1.f - fw;
        const float wh1 = fh, wh0 = 1.f - fh;
        const float wd1 = fd, wd0 = 1.f - fd;
        const float c00 = wd0 * wh0, c01 = wd0 * wh1;
        const float c10 = wd1 * wh0, c11 = wd1 * wh1;

        acc0 = c00 * (ww0 * r00[0] + ww1 * r00[3])
             + c01 * (ww0 * r01[0] + ww1 * r01[3])
             + c10 * (ww0 * r10[0] + ww1 * r10[3])
             + c11 * (ww0 * r11[0] + ww1 * r11[3]);
        acc1 = c00 * (ww0 * r00[1] + ww1 * r00[4])
             + c01 * (ww0 * r01[1] + ww1 * r01[4])
             + c10 * (ww0 * r10[1] + ww1 * r10[4])
             + c11 * (ww0 * r11[1] + ww1 * r11[4]);
        acc2 = c00 * (ww0 * r00[2] + ww1 * r00[5])
             + c01 * (ww0 * r01[2] + ww1 * r01[5])
             + c10 * (ww0 * r10[2] + ww1 * r10[5])
             + c11 * (ww0 * r11[2] + ww1 * r11[5]);
    } else {
        // sample left the staged box: per-corner global gather w/ zero padding
        acc0 = acc1 = acc2 = 0.f;
#pragma unroll
        for (int dz = 0; dz < 2; ++dz) {
            const int cd = d0 + dz;
            if ((unsigned)cd >= (unsigned)D_) continue;
            const float wz = dz ? fd : (1.f - fd);
#pragma unroll
            for (int dy = 0; dy < 2; ++dy) {
                const int ch = h0 + dy;
                if ((unsigned)ch >= (unsigned)H_) continue;
                const float wzy = wz * (dy ? fh : (1.f - fh));
                const int rowbase = (cd * H_ + ch) * W_;
#pragma unroll
                for (int dx = 0; dx < 2; ++dx) {
                    const int cw = w0 + dx;
                    if ((unsigned)cw >= (unsigned)W_) continue;
                    const float wt = wzy * (dx ? fw : (1.f - fw));
                    if (FIRST) {
                        const int j = rowbase + cw;
                        acc0 += wt * in[j];
                        acc1 += wt * in[NV + j];
                        acc2 += wt * in[2 * NV + j];
                    } else {
                        const int j = (rowbase + cw) * 3;
                        acc0 += wt * in[j];
                        acc1 += wt * in[j + 1];
                        acc2 += wt * in[j + 2];
                    }
                }
            }
        }
        if (FIRST) { acc0 *= S_; acc1 *= S_; acc2 *= S_; }
    }

    const float o0 = f0 + acc0;
    const float o1 = f1 + acc1;
    const float o2 = f2 + acc2;
    if (PLANAR_OUT) {
        out[idx]          = o0;
        out[NV + idx]     = o1;
        out[2 * NV + idx] = o2;
    } else {
        out[3 * idx]     = o0;
        out[3 * idx + 1] = o1;
        out[3 * idx + 2] = o2;
    }
}

extern "C" void kernel_launch(void* const* d_in, const int* in_sizes, int n_in,
                              void* d_out, int out_size, void* d_ws, size_t ws_size,
                              hipStream_t stream) {
    const float* svf = (const float*)d_in[0];
    float* outp = (float*)d_out;   // doubles as interleaved scratch
    float* wsA  = (float*)d_ws;

    dim3 blk(TW, TH, TD);
    dim3 grd(W_ / TW, H_ / TH, D_ / TD);   // (7, 24, 80)

    // k0: svf(planar, scale folded) -> outp; then ping-pong; k6 planar -> outp
    compose_k<1, 0><<<grd, blk, 0, stream>>>(svf, outp);
    compose_k<0, 0><<<grd, blk, 0, stream>>>(outp, wsA);
    compose_k<0, 0><<<grd, blk, 0, stream>>>(wsA, outp);
    compose_k<0, 0><<<grd, blk, 0, stream>>>(outp, wsA);
    compose_k<0, 0><<<grd, blk, 0, stream>>>(wsA, outp);
    compose_k<0, 0><<<grd, blk, 0, stream>>>(outp, wsA);
    compose_k<0, 1><<<grd, blk, 0, stream>>>(wsA, outp);
}

// Round 7
// 286.243 us; speedup vs baseline: 1.6358x; 1.6358x over previous
//
#include <hip/hip_runtime.h>
#include <hip/hip_fp16.h>

// Integration_block: scaling-and-squaring SVF integration.
// flow = SVF * 2^-7; 7x: flow = flow + trilerp(flow, p + flow), zeros padding.
// Shape (1, 3, 160, 192, 224) fp32 planar in/out.
//
// Intermediates: fp16, xyz-tight-interleaved (6 B/voxel) -> halves the
// per-pass HBM/L3 traffic (the R4 counters show 160 MB/pass streaming below
// L2 at ~2.6 TB/s = the bottleneck). 6 B granularity handled with covering
// loads: read the 4B-aligned 16B window, funnel-shift by half-parity.
// Precision: rel 4.9e-4/store, errors scale with the doubling signal ->
// final abs err ~ 3 * 4.9e-4 * 7 ~ 0.01, threshold 4.4e-2.

#define D_ 160
#define H_ 192
#define W_ 224
static constexpr int NV = D_ * H_ * W_;   // 6,881,280
static constexpr float S_ = 0.0078125f;   // 2^-7
typedef unsigned int u32;

struct __attribute__((packed, aligned(4))) U4 { u32 a, b, c, d; };
struct __attribute__((packed, aligned(4))) U2 { u32 a, b; };

__device__ __forceinline__ float2 h2f(u32 h) {
    __half2 x = *(__half2*)&h;
    return __half22float2(x);
}
__device__ __forceinline__ u32 pk(float a, float b) {
    __half2 h = __floats2half2_rn(a, b);
    return *(u32*)&h;
}
__device__ __forceinline__ float h1f(u32 bits16) {
    __half_raw r; r.x = (unsigned short)bits16;
    return __half2float(__half(r));
}

// planar fp32 SVF -> tight fp16 interleaved, scale folded. 4 voxels/thread.
__global__ __launch_bounds__(256) void scale_k(const float* __restrict__ svf,
                                               u32* __restrict__ out) {
    const int i = blockIdx.x * 256 + threadIdx.x;   // NV/4 = 1,720,320 ids
    float4 a = ((const float4*)svf)[i];
    float4 b = ((const float4*)(svf + NV))[i];
    float4 c = ((const float4*)(svf + 2 * NV))[i];
    u32* o = out + 6 * (size_t)i;
    o[0] = pk(a.x * S_, b.x * S_);
    o[1] = pk(c.x * S_, a.y * S_);
    o[2] = pk(b.y * S_, c.y * S_);
    o[3] = pk(a.z * S_, b.z * S_);
    o[4] = pk(c.z * S_, a.w * S_);
    o[5] = pk(b.w * S_, c.w * S_);
}

template <int PLANAR_OUT>
__global__ __launch_bounds__(256) void compose_k(const u32* __restrict__ in,
                                                 void* __restrict__ out_) {
    const int w = blockIdx.x * 32 + threadIdx.x;   // 224/32 = 7
    const int h = blockIdx.y * 4 + threadIdx.y;    // 192/4  = 48
    const int d = blockIdx.z * 2 + threadIdx.z;    // 160/2  = 80
    const int idx = (d * H_ + h) * W_ + w;

    // own flow: halves [3idx, 3idx+2]
    const int Ho = 3 * idx;
    const U2 uo = *(const U2*)(in + (Ho >> 1));
    const int so = Ho & 1;
    const u32 vo = so ? ((uo.a >> 16) | (uo.b << 16)) : uo.a;
    const float2 xy = h2f(vo);
    const float f0 = xy.x;
    const float f1 = xy.y;
    const float f2 = h1f(so ? (uo.b >> 16) : (uo.b & 0xffffu));

    const float pd = (float)d + f0;
    const float ph = (float)h + f1;
    const float pw = (float)w + f2;
    const float d0f = floorf(pd), h0f = floorf(ph), w0f = floorf(pw);
    const int d0 = (int)d0f, h0 = (int)h0f, w0 = (int)w0f;
    const float fd = pd - d0f, fh = ph - h0f, fw = pw - w0f;

    float acc0, acc1, acc2;

    const bool interior = ((unsigned)d0 <= (unsigned)(D_ - 2)) &
                          ((unsigned)h0 <= (unsigned)(H_ - 2)) &
                          ((unsigned)w0 <= (unsigned)(W_ - 2));

    if (interior) {
        const int j00 = (d0 * H_ + h0) * W_ + w0;
        const int j01 = j00 + W_;
        const int j10 = j00 + H_ * W_;
        const int j11 = j10 + W_;
        const int H00 = 3 * j00, H01 = 3 * j01, H10 = 3 * j10, H11 = 3 * j11;
        // issue all 4 covering loads up front
        const U4 u0 = *(const U4*)(in + (H00 >> 1));
        const U4 u1 = *(const U4*)(in + (H01 >> 1));
        const U4 u2 = *(const U4*)(in + (H10 >> 1));
        const U4 u3 = *(const U4*)(in + (H11 >> 1));

        const float ww1 = fw, ww0 = 1.f - fw;
        const float wh1 = fh, wh0 = 1.f - fh;
        const float wd1 = fd, wd0 = 1.f - fd;
        const float c00 = wd0 * wh0, c01 = wd0 * wh1;
        const float c10 = wd1 * wh0, c11 = wd1 * wh1;

        acc0 = 0.f; acc1 = 0.f; acc2 = 0.f;

        // extract 6 halves (two voxels' xyz) from a 16B window, shifted by parity
        {
            const int s = H00 & 1;
            const u32 v0 = s ? ((u0.a >> 16) | (u0.b << 16)) : u0.a;
            const u32 v1 = s ? ((u0.b >> 16) | (u0.c << 16)) : u0.b;
            const u32 v2 = s ? ((u0.c >> 16) | (u0.d << 16)) : u0.c;
            const float2 p0 = h2f(v0);   // x0 y0
            const float2 p1 = h2f(v1);   // z0 x1
            const float2 p2 = h2f(v2);   // y1 z1
            acc0 += c00 * (ww0 * p0.x + ww1 * p1.y);
            acc1 += c00 * (ww0 * p0.y + ww1 * p2.x);
            acc2 += c00 * (ww0 * p1.x + ww1 * p2.y);
        }
        {
            const int s = H01 & 1;
            const u32 v0 = s ? ((u1.a >> 16) | (u1.b << 16)) : u1.a;
            const u32 v1 = s ? ((u1.b >> 16) | (u1.c << 16)) : u1.b;
            const u32 v2 = s ? ((u1.c >> 16) | (u1.d << 16)) : u1.c;
            const float2 p0 = h2f(v0);
            const float2 p1 = h2f(v1);
            const float2 p2 = h2f(v2);
            acc0 += c01 * (ww0 * p0.x + ww1 * p1.y);
            acc1 += c01 * (ww0 * p0.y + ww1 * p2.x);
            acc2 += c01 * (ww0 * p1.x + ww1 * p2.y);
        }
        {
            const int s = H10 & 1;
            const u32 v0 = s ? ((u2.a >> 16) | (u2.b << 16)) : u2.a;
            const u32 v1 = s ? ((u2.b >> 16) | (u2.c << 16)) : u2.b;
            const u32 v2 = s ? ((u2.c >> 16) | (u2.d << 16)) : u2.c;
            const float2 p0 = h2f(v0);
            const float2 p1 = h2f(v1);
            const float2 p2 = h2f(v2);
            acc0 += c10 * (ww0 * p0.x + ww1 * p1.y);
            acc1 += c10 * (ww0 * p0.y + ww1 * p2.x);
            acc2 += c10 * (ww0 * p1.x + ww1 * p2.y);
        }
        {
            const int s = H11 & 1;
            const u32 v0 = s ? ((u3.a >> 16) | (u3.b << 16)) : u3.a;
            const u32 v1 = s ? ((u3.b >> 16) | (u3.c << 16)) : u3.b;
            const u32 v2 = s ? ((u3.c >> 16) | (u3.d << 16)) : u3.c;
            const float2 p0 = h2f(v0);
            const float2 p1 = h2f(v1);
            const float2 p2 = h2f(v2);
            acc0 += c11 * (ww0 * p0.x + ww1 * p1.y);
            acc1 += c11 * (ww0 * p0.y + ww1 * p2.x);
            acc2 += c11 * (ww0 * p1.x + ww1 * p2.y);
        }
    } else {
        // boundary: per-corner bounds-checked gather (zeros padding)
        acc0 = acc1 = acc2 = 0.f;
        const __half* hp = (const __half*)in;
#pragma unroll
        for (int dz = 0; dz < 2; ++dz) {
            const int cd = d0 + dz;
            if ((unsigned)cd >= (unsigned)D_) continue;
            const float wz = dz ? fd : (1.f - fd);
#pragma unroll
            for (int dy = 0; dy < 2; ++dy) {
                const int ch = h0 + dy;
                if ((unsigned)ch >= (unsigned)H_) continue;
                const float wzy = wz * (dy ? fh : (1.f - fh));
                const int rowbase = (cd * H_ + ch) * W_;
#pragma unroll
                for (int dx = 0; dx < 2; ++dx) {
                    const int cw = w0 + dx;
                    if ((unsigned)cw >= (unsigned)W_) continue;
                    const float wt = wzy * (dx ? fw : (1.f - fw));
                    const int j = 3 * (rowbase + cw);
                    acc0 += wt * __half2float(hp[j]);
                    acc1 += wt * __half2float(hp[j + 1]);
                    acc2 += wt * __half2float(hp[j + 2]);
                }
            }
        }
    }

    const float o0 = f0 + acc0;
    const float o1 = f1 + acc1;
    const float o2 = f2 + acc2;
    if (PLANAR_OUT) {
        float* out = (float*)out_;
        out[idx]          = o0;
        out[NV + idx]     = o1;
        out[2 * NV + idx] = o2;
    } else {
        __half* out = (__half*)out_;
        out[3 * idx]     = __float2half_rn(o0);
        out[3 * idx + 1] = __float2half_rn(o1);
        out[3 * idx + 2] = __float2half_rn(o2);
    }
}

extern "C" void kernel_launch(void* const* d_in, const int* in_sizes, int n_in,
                              void* d_out, int out_size, void* d_ws, size_t ws_size,
                              hipStream_t stream) {
    const float* svf = (const float*)d_in[0];
    float* outp = (float*)d_out;           // final planar fp32 output
    u32* X0 = (u32*)d_ws;                  // fp16 scratch A (41.3 MB + slack)
    u32* X1 = (u32*)d_out;                 // fp16 scratch B lives in d_out until last pass

    scale_k<<<NV / 4 / 256, 256, 0, stream>>>(svf, X0);

    dim3 blk(32, 4, 2);
    dim3 grd(W_ / 32, H_ / 4, D_ / 2);     // (7, 48, 80)

    // reads alternate X0,X1,... ; c6 reads X0 and writes planar fp32 to d_out
    compose_k<0><<<grd, blk, 0, stream>>>(X0, X1);
    compose_k<0><<<grd, blk, 0, stream>>>(X1, X0);
    compose_k<0><<<grd, blk, 0, stream>>>(X0, X1);
    compose_k<0><<<grd, blk, 0, stream>>>(X1, X0);
    compose_k<0><<<grd, blk, 0, stream>>>(X0, X1);
    compose_k<0><<<grd, blk, 0, stream>>>(X1, X0);
    compose_k<1><<<grd, blk, 0, stream>>>(X0, outp);
}